// Round 4
// baseline (1881.637 us; speedup 1.0000x reference)
//
#include <hip/hip_runtime.h>

#define D 256

typedef __attribute__((ext_vector_type(8))) short bf16x8;
typedef __attribute__((ext_vector_type(4))) float f32x4;

__device__ inline unsigned short f2bf(float f) {
  union { float f; unsigned u; } v; v.f = f;
  unsigned r = v.u + 0x7FFFu + ((v.u >> 16) & 1u);
  return (unsigned short)(r >> 16);
}
__device__ inline float bf2f(unsigned short u) {
  union { unsigned u; float f; } v; v.u = ((unsigned)u) << 16;
  return v.f;
}

// async global->LDS, 16B per lane. ldst must be wave-uniform; data lands at
// ldst + lane*16. gsrc is per-lane.
__device__ inline void gl_lds16(const void* gsrc, void* ldst) {
  __builtin_amdgcn_global_load_lds(
      (const __attribute__((address_space(1))) void*)gsrc,
      (__attribute__((address_space(3))) void*)ldst, 16, 0, 0);
}

// Convert fp32 W[b][k][n] -> bf16 Wt[b][n][k]
__global__ void wprep_kernel(const float* __restrict__ w, unsigned short* __restrict__ wt,
                             int K, int total) {
  int idx = blockIdx.x * 256 + threadIdx.x;
  if (idx >= total) return;
  int k = idx % K;
  int rest = idx / K;
  int n = rest % D;
  int b = rest / D;
  float f = w[((size_t)b * K + k) * D + n];
  wt[idx] = f2bf(f);
}

__global__ void cvt_bf16_kernel(const float4* __restrict__ in, ushort4* __restrict__ out, int n4) {
  int i = blockIdx.x * 256 + threadIdx.x;
  if (i >= n4) return;
  float4 f = in[i];
  ushort4 o;
  o.x = f2bf(f.x); o.y = f2bf(f.y); o.z = f2bf(f.z); o.w = f2bf(f.w);
  out[i] = o;
}

// ---- CSR build ----
__global__ void hist_kernel(const int* __restrict__ dst, int* __restrict__ hist, int E) {
  int i = blockIdx.x * 256 + threadIdx.x;
  if (i < E) atomicAdd(&hist[dst[i]], 1);
}

__global__ void scan_kernel(const int* __restrict__ hist, int* __restrict__ offs, int Nn) {
  __shared__ int part[256];
  int t = threadIdx.x;
  int chunk = (Nn + 255) >> 8;
  int s = t * chunk;
  int e = s + chunk; if (e > Nn) e = Nn; if (s > Nn) s = Nn;
  int sum = 0;
  for (int i = s; i < e; ++i) sum += hist[i];
  part[t] = sum;
  __syncthreads();
  if (t == 0) {
    int run = 0;
    for (int i = 0; i < 256; ++i) { int v = part[i]; part[i] = run; run += v; }
  }
  __syncthreads();
  int run = part[t];
  for (int i = s; i < e; ++i) { offs[i] = run; run += hist[i]; }
  if (e == Nn) offs[Nn] = run;
}

__global__ void fill_kernel(const int* __restrict__ dst, const int* __restrict__ offs,
                            int* __restrict__ cnt, int* __restrict__ eid, int E) {
  int i = blockIdx.x * 256 + threadIdx.x;
  if (i < E) {
    int d = dst[i];
    int p = offs[d] + atomicAdd(&cnt[d], 1);
    eid[p] = i;
  }
}

// agg[node] = sum over CSR bucket of eabf rows (bf16 in, bf16 out). One wave/node.
__global__ __launch_bounds__(256) void agg_kernel(
    const unsigned short* __restrict__ eabf, const int* __restrict__ eid,
    const int* __restrict__ offs, unsigned short* __restrict__ aggbf, int Nn) {
  int node = blockIdx.x * 4 + (threadIdx.x >> 6);
  if (node >= Nn) return;
  int lane = threadIdx.x & 63;
  int s = offs[node], e = offs[node + 1];
  float4 acc = make_float4(0.f, 0.f, 0.f, 0.f);
  for (int i = s; i < e; ++i) {
    int ed = eid[i];
    ushort4 v = *(const ushort4*)(eabf + (size_t)ed * D + lane * 4);
    acc.x += bf2f(v.x); acc.y += bf2f(v.y); acc.z += bf2f(v.z); acc.w += bf2f(v.w);
  }
  ushort4 o;
  o.x = f2bf(acc.x); o.y = f2bf(acc.y); o.z = f2bf(acc.z); o.w = f2bf(acc.w);
  *(ushort4*)(aggbf + (size_t)node * D + lane * 4) = o;
}

// Fused 3-layer MLP: res += LN(relu(relu(A@W1+b1)@W2+b2)@W3+b3)*g+b
// A = concat of nChunk bf16 256-wide chunks (optional row gather g0/g1).
// h1,h2 live in LDS. If resid!=null: fp32 RMW (+ optional bf16 shadow bfout).
// Else: bf16 RMW directly on bfout.
__global__ __launch_bounds__(256) void fused_mlp(
    const unsigned short* __restrict__ C0, const int* __restrict__ g0,
    const unsigned short* __restrict__ C1, const int* __restrict__ g1,
    const unsigned short* __restrict__ C2,
    int nChunk,
    const unsigned short* __restrict__ W1, const float* __restrict__ b1,
    const unsigned short* __restrict__ W2, const float* __restrict__ b2,
    const unsigned short* __restrict__ W3, const float* __restrict__ b3,
    const float* __restrict__ lng, const float* __restrict__ lnb,
    float* __restrict__ resid, unsigned short* __restrict__ bfout, int M)
{
  // LDS budget 54272 B -> 3 blocks/CU. As (L1 staging) aliases ps1/ps2 (LN epi).
  __shared__ __align__(16) unsigned short Bs[256 * 32];   // 16384 B, unpadded (global_load_lds)
  __shared__ __align__(16) unsigned short Hs[64 * 264];   // 33792 B, h1/h2, +8 pad
  __shared__ __align__(16) unsigned short AsPs[64 * 32];  // 4096 B: As | ps1/ps2
  unsigned short* As = AsPs;
  float* ps1 = (float*)AsPs;          // [64][4]
  float* ps2 = (float*)AsPs + 256;    // [64][4]

  const int tid  = threadIdx.x;
  const int lane = tid & 63;
  const int wave = tid >> 6;
  const int lr   = lane & 15;
  const int lq   = lane >> 4;
  const int r0   = blockIdx.x * 64;

  const int ra = tid >> 2;            // 0..63: A-row / B-n-row this lane stages
  const int ka = (tid & 3) << 3;      // 8-elem k offset within 32-wide tile
  int rowA = r0 + ra;
  if (rowA > M - 1) rowA = M - 1;
  const int row0 = g0 ? g0[rowA] : rowA;
  const int row1 = g1 ? g1[rowA] : rowA;

  f32x4 acc[4][4];
  bf16x8 af[4], bq[4];

  // ---------------- Layer 1 (K = nChunk*256, A from global) ----------------
  #pragma unroll
  for (int i = 0; i < 4; i++)
    #pragma unroll
    for (int j = 0; j < 4; j++)
      acc[i][j] = (f32x4){0.f, 0.f, 0.f, 0.f};

  const int K1 = nChunk << 8;
  const int nkt1 = K1 >> 5;
  for (int kt = 0; kt < nkt1; ++kt) {
    const int chunk = kt >> 3;
    const int kloc  = (kt & 7) << 5;
    const unsigned short* base = (chunk == 0) ? C0 : (chunk == 1 ? C1 : C2);
    const int row = (chunk == 0) ? row0 : (chunk == 1 ? row1 : rowA);
    gl_lds16(base + (size_t)row * D + kloc + ka, &As[wave * 512]);
    #pragma unroll
    for (int q = 0; q < 4; ++q)
      gl_lds16(W1 + (size_t)(q * 64 + ra) * K1 + (kt << 5) + ka,
               &Bs[(q * 64 + wave * 16) * 32]);
    __syncthreads();

    #pragma unroll
    for (int mt = 0; mt < 4; ++mt)
      af[mt] = *(const bf16x8*)&As[(mt * 16 + lr) * 32 + lq * 8];
    #pragma unroll
    for (int nt = 0; nt < 4; ++nt)
      bq[nt] = *(const bf16x8*)&Bs[(wave * 64 + nt * 16 + lr) * 32 + lq * 8];
    #pragma unroll
    for (int mt = 0; mt < 4; ++mt)
      #pragma unroll
      for (int nt = 0; nt < 4; ++nt)
        acc[mt][nt] = __builtin_amdgcn_mfma_f32_16x16x32_bf16(af[mt], bq[nt], acc[mt][nt], 0, 0, 0);
    __syncthreads();
  }
  // epilogue: bias + relu -> Hs
  {
    float bv[4];
    #pragma unroll
    for (int nt = 0; nt < 4; ++nt) bv[nt] = b1[wave * 64 + nt * 16 + lr];
    #pragma unroll
    for (int mt = 0; mt < 4; ++mt)
      #pragma unroll
      for (int r = 0; r < 4; ++r) {
        const int row = mt * 16 + lq * 4 + r;
        #pragma unroll
        for (int nt = 0; nt < 4; ++nt) {
          float v = acc[mt][nt][r] + bv[nt];
          v = v > 0.f ? v : 0.f;
          Hs[row * 264 + wave * 64 + nt * 16 + lr] = f2bf(v);
        }
      }
  }

  // ---------------- Layer 2 (K = 256, A from Hs) ----------------
  #pragma unroll
  for (int i = 0; i < 4; i++)
    #pragma unroll
    for (int j = 0; j < 4; j++)
      acc[i][j] = (f32x4){0.f, 0.f, 0.f, 0.f};
  for (int kt = 0; kt < 8; ++kt) {
    #pragma unroll
    for (int q = 0; q < 4; ++q)
      gl_lds16(W2 + (size_t)(q * 64 + ra) * D + (kt << 5) + ka,
               &Bs[(q * 64 + wave * 16) * 32]);
    __syncthreads();   // also orders Hs writes (L1 epi) before Hs reads
    #pragma unroll
    for (int mt = 0; mt < 4; ++mt)
      af[mt] = *(const bf16x8*)&Hs[(mt * 16 + lr) * 264 + (kt << 5) + lq * 8];
    #pragma unroll
    for (int nt = 0; nt < 4; ++nt)
      bq[nt] = *(const bf16x8*)&Bs[(wave * 64 + nt * 16 + lr) * 32 + lq * 8];
    #pragma unroll
    for (int mt = 0; mt < 4; ++mt)
      #pragma unroll
      for (int nt = 0; nt < 4; ++nt)
        acc[mt][nt] = __builtin_amdgcn_mfma_f32_16x16x32_bf16(af[mt], bq[nt], acc[mt][nt], 0, 0, 0);
    __syncthreads();
  }
  {
    float bv[4];
    #pragma unroll
    for (int nt = 0; nt < 4; ++nt) bv[nt] = b2[wave * 64 + nt * 16 + lr];
    #pragma unroll
    for (int mt = 0; mt < 4; ++mt)
      #pragma unroll
      for (int r = 0; r < 4; ++r) {
        const int row = mt * 16 + lq * 4 + r;
        #pragma unroll
        for (int nt = 0; nt < 4; ++nt) {
          float v = acc[mt][nt][r] + bv[nt];
          v = v > 0.f ? v : 0.f;
          Hs[row * 264 + wave * 64 + nt * 16 + lr] = f2bf(v);
        }
      }
  }

  // ---------------- Layer 3 (K = 256, A from Hs) + LayerNorm + residual ----
  #pragma unroll
  for (int i = 0; i < 4; i++)
    #pragma unroll
    for (int j = 0; j < 4; j++)
      acc[i][j] = (f32x4){0.f, 0.f, 0.f, 0.f};
  for (int kt = 0; kt < 8; ++kt) {
    #pragma unroll
    for (int q = 0; q < 4; ++q)
      gl_lds16(W3 + (size_t)(q * 64 + ra) * D + (kt << 5) + ka,
               &Bs[(q * 64 + wave * 16) * 32]);
    __syncthreads();
    #pragma unroll
    for (int mt = 0; mt < 4; ++mt)
      af[mt] = *(const bf16x8*)&Hs[(mt * 16 + lr) * 264 + (kt << 5) + lq * 8];
    #pragma unroll
    for (int nt = 0; nt < 4; ++nt)
      bq[nt] = *(const bf16x8*)&Bs[(wave * 64 + nt * 16 + lr) * 32 + lq * 8];
    #pragma unroll
    for (int mt = 0; mt < 4; ++mt)
      #pragma unroll
      for (int nt = 0; nt < 4; ++nt)
        acc[mt][nt] = __builtin_amdgcn_mfma_f32_16x16x32_bf16(af[mt], bq[nt], acc[mt][nt], 0, 0, 0);
    __syncthreads();
  }
  // bias
  #pragma unroll
  for (int nt = 0; nt < 4; ++nt) {
    const float bv = b3[wave * 64 + nt * 16 + lr];
    #pragma unroll
    for (int mt = 0; mt < 4; ++mt)
      #pragma unroll
      for (int r = 0; r < 4; ++r)
        acc[mt][nt][r] += bv;
  }
  // LN stats (ps aliases As -- As is dead after L1; barrier above separates)
  #pragma unroll
  for (int mt = 0; mt < 4; ++mt) {
    #pragma unroll
    for (int r = 0; r < 4; ++r) {
      float s1 = 0.f, s2 = 0.f;
      #pragma unroll
      for (int nt = 0; nt < 4; ++nt) {
        float v = acc[mt][nt][r];
        s1 += v; s2 += v * v;
      }
      #pragma unroll
      for (int dlt = 1; dlt < 16; dlt <<= 1) {
        s1 += __shfl_xor(s1, dlt, 64);
        s2 += __shfl_xor(s2, dlt, 64);
      }
      if (lr == 0) {
        ps1[(mt * 16 + lq * 4 + r) * 4 + wave] = s1;
        ps2[(mt * 16 + lq * 4 + r) * 4 + wave] = s2;
      }
    }
  }
  __syncthreads();
  #pragma unroll
  for (int mt = 0; mt < 4; ++mt) {
    #pragma unroll
    for (int r = 0; r < 4; ++r) {
      const int rl = mt * 16 + lq * 4 + r;
      const int row = r0 + rl;
      float fs1 = ps1[rl * 4 + 0] + ps1[rl * 4 + 1] + ps1[rl * 4 + 2] + ps1[rl * 4 + 3];
      float fs2 = ps2[rl * 4 + 0] + ps2[rl * 4 + 1] + ps2[rl * 4 + 2] + ps2[rl * 4 + 3];
      float mean = fs1 * (1.f / 256.f);
      float var  = fs2 * (1.f / 256.f) - mean * mean;
      float rstd = rsqrtf(var + 1e-5f);
      if (row < M) {
        #pragma unroll
        for (int nt = 0; nt < 4; ++nt) {
          const int col = wave * 64 + nt * 16 + lr;
          float v = (acc[mt][nt][r] - mean) * rstd * lng[col] + lnb[col];
          if (resid) {
            float* rp = resid + (size_t)row * D + col;
            float nv = *rp + v;
            *rp = nv;
            if (bfout) bfout[(size_t)row * D + col] = f2bf(nv);
          } else {
            unsigned short* bp = bfout + (size_t)row * D + col;
            *bp = f2bf(bf2f(*bp) + v);
          }
        }
      }
    }
  }
}

extern "C" void kernel_launch(void* const* d_in, const int* in_sizes, int n_in,
                              void* d_out, int out_size, void* d_ws, size_t ws_size,
                              hipStream_t stream) {
  const float* x         = (const float*)d_in[0];
  const int*   eidx      = (const int*)d_in[1];
  const float* edge_attr = (const float*)d_in[2];
  const float* eW1 = (const float*)d_in[3];
  const float* eB1 = (const float*)d_in[4];
  const float* eW2 = (const float*)d_in[5];
  const float* eB2 = (const float*)d_in[6];
  const float* eW3 = (const float*)d_in[7];
  const float* eB3 = (const float*)d_in[8];
  const float* eLNg = (const float*)d_in[9];
  const float* eLNb = (const float*)d_in[10];
  const float* nW1 = (const float*)d_in[11];
  const float* nB1 = (const float*)d_in[12];
  const float* nW2 = (const float*)d_in[13];
  const float* nB2 = (const float*)d_in[14];
  const float* nW3 = (const float*)d_in[15];
  const float* nB3 = (const float*)d_in[16];
  const float* nLNg = (const float*)d_in[17];
  const float* nLNb = (const float*)d_in[18];

  const int Nn = in_sizes[0] / D;   // 10000
  const int E  = in_sizes[1] / 2;   // 60000
  const int B  = in_sizes[4] / D;   // 9

  const int* srcI = eidx;
  const int* dstI = eidx + E;

  char* wsp = (char*)d_ws;
  size_t off = 0;
  auto alloc = [&](size_t bytes) {
    char* p = wsp + off;
    off += (bytes + 255) & ~(size_t)255;
    return p;
  };
  unsigned short* eW1t = (unsigned short*)alloc((size_t)B * 768 * D * 2);
  unsigned short* eW2t = (unsigned short*)alloc((size_t)B * 256 * D * 2);
  unsigned short* eW3t = (unsigned short*)alloc((size_t)B * 256 * D * 2);
  unsigned short* nW1t = (unsigned short*)alloc((size_t)B * 512 * D * 2);
  unsigned short* nW2t = (unsigned short*)alloc((size_t)B * 256 * D * 2);
  unsigned short* nW3t = (unsigned short*)alloc((size_t)B * 256 * D * 2);
  unsigned short* eabf  = (unsigned short*)alloc((size_t)E * D * 2);
  unsigned short* xbf   = (unsigned short*)alloc((size_t)Nn * D * 2);
  unsigned short* aggbf = (unsigned short*)alloc((size_t)Nn * D * 2);
  int*            hist  = (int*)alloc((size_t)(Nn + 1) * 4);
  int*            offs  = (int*)alloc((size_t)(Nn + 1) * 4);
  int*            cnt   = (int*)alloc((size_t)Nn * 4);
  int*            eid   = (int*)alloc((size_t)E * 4);

  float* xbuf = (float*)d_out;  // x state lives in d_out

  auto wp = [&](const float* w, unsigned short* wt, int K) {
    int total = B * K * D;
    wprep_kernel<<<(total + 255) / 256, 256, 0, stream>>>(w, wt, K, total);
  };
  wp(eW1, eW1t, 768);
  wp(eW2, eW2t, 256);
  wp(eW3, eW3t, 256);
  wp(nW1, nW1t, 512);
  wp(nW2, nW2t, 256);
  wp(nW3, nW3t, 256);

  hipMemcpyAsync(xbuf, x, (size_t)Nn * D * 4, hipMemcpyDeviceToDevice, stream);
  {
    int n4 = E * D / 4;
    cvt_bf16_kernel<<<(n4 + 255) / 256, 256, 0, stream>>>(
        (const float4*)edge_attr, (ushort4*)eabf, n4);
    int m4 = Nn * D / 4;
    cvt_bf16_kernel<<<(m4 + 255) / 256, 256, 0, stream>>>(
        (const float4*)x, (ushort4*)xbf, m4);
  }

  // CSR build (edge_index constant across blocks -> once per launch)
  hipMemsetAsync(hist, 0, (size_t)Nn * 4, stream);
  hipMemsetAsync(cnt, 0, (size_t)Nn * 4, stream);
  hist_kernel<<<(E + 255) / 256, 256, 0, stream>>>(dstI, hist, E);
  scan_kernel<<<1, 256, 0, stream>>>(hist, offs, Nn);
  fill_kernel<<<(E + 255) / 256, 256, 0, stream>>>(dstI, offs, cnt, eid, E);

  const int gridE = (E + 63) / 64;
  const int gridN = (Nn + 63) / 64;
  const int gridA = (Nn + 3) / 4;

  for (int b = 0; b < B; ++b) {
    // edge: ea += LN(MLP([x[src], x[dst], ea]))  -- bf16 state RMW in eabf
    fused_mlp<<<gridE, 256, 0, stream>>>(
        xbf, srcI, xbf, dstI, eabf, /*nChunk*/3,
        eW1t + (size_t)b * 768 * D, eB1 + b * D,
        eW2t + (size_t)b * 256 * D, eB2 + b * D,
        eW3t + (size_t)b * 256 * D, eB3 + b * D,
        eLNg + b * D, eLNb + b * D, nullptr, eabf, E);
    // agg = segment_sum(ea, dst) via CSR gather (bf16 out)
    agg_kernel<<<gridA, 256, 0, stream>>>(eabf, eid, offs, aggbf, Nn);
    // node: x += LN(MLP([x, agg]))  -- fp32 RMW in xbuf + bf16 shadow xbf
    fused_mlp<<<gridN, 256, 0, stream>>>(
        xbf, nullptr, aggbf, nullptr, nullptr, /*nChunk*/2,
        nW1t + (size_t)b * 512 * D, nB1 + b * D,
        nW2t + (size_t)b * 256 * D, nB2 + b * D,
        nW3t + (size_t)b * 256 * D, nB3 + b * D,
        nLNg + b * D, nLNb + b * D, xbuf, xbf, Nn);
  }
}

// Round 5
// 1838.851 us; speedup vs baseline: 1.0233x; 1.0233x over previous
//
#include <hip/hip_runtime.h>

#define D 256

typedef __attribute__((ext_vector_type(8))) short bf16x8;
typedef __attribute__((ext_vector_type(4))) float f32x4;

__device__ inline unsigned short f2bf(float f) {
  union { float f; unsigned u; } v; v.f = f;
  unsigned r = v.u + 0x7FFFu + ((v.u >> 16) & 1u);
  return (unsigned short)(r >> 16);
}
__device__ inline float bf2f(unsigned short u) {
  union { unsigned u; float f; } v; v.u = ((unsigned)u) << 16;
  return v.f;
}

// Convert fp32 W[b][k][n] (n==D) -> bf16 fragment-major W':
//   W'[((kt*(D/16)+ct)*64 + lane)*8 + j]  where k=kt*32+(lane>>4)*8+j, col=ct*16+(lane&15)
// so a wave's bq[nt] load for (kt, ct=wave*4+nt) is one contiguous 1KB segment.
__global__ void wprep_kernel(const float* __restrict__ w, unsigned short* __restrict__ wt,
                             int K, int total) {
  int idx = blockIdx.x * 256 + threadIdx.x;
  if (idx >= total) return;
  int per_b = K * D;
  int b = idx / per_b;
  int r = idx % per_b;
  int j = r & 7;
  int lane = (r >> 3) & 63;
  int t = r >> 9;            // kt*16 + ct
  int kt = t >> 4, ct = t & 15;
  int k = kt * 32 + (lane >> 4) * 8 + j;
  int col = ct * 16 + (lane & 15);
  wt[idx] = f2bf(w[((size_t)b * K + k) * D + col]);
}

__global__ void cvt_bf16_kernel(const float4* __restrict__ in, ushort4* __restrict__ out, int n4) {
  int i = blockIdx.x * 256 + threadIdx.x;
  if (i >= n4) return;
  float4 f = in[i];
  ushort4 o;
  o.x = f2bf(f.x); o.y = f2bf(f.y); o.z = f2bf(f.z); o.w = f2bf(f.w);
  out[i] = o;
}

// ---- CSR build ----
__global__ void hist_kernel(const int* __restrict__ dst, int* __restrict__ hist, int E) {
  int i = blockIdx.x * 256 + threadIdx.x;
  if (i < E) atomicAdd(&hist[dst[i]], 1);
}

__global__ void scan_kernel(const int* __restrict__ hist, int* __restrict__ offs, int Nn) {
  __shared__ int part[256];
  int t = threadIdx.x;
  int chunk = (Nn + 255) >> 8;
  int s = t * chunk;
  int e = s + chunk; if (e > Nn) e = Nn; if (s > Nn) s = Nn;
  int sum = 0;
  for (int i = s; i < e; ++i) sum += hist[i];
  part[t] = sum;
  __syncthreads();
  if (t == 0) {
    int run = 0;
    for (int i = 0; i < 256; ++i) { int v = part[i]; part[i] = run; run += v; }
  }
  __syncthreads();
  int run = part[t];
  for (int i = s; i < e; ++i) { offs[i] = run; run += hist[i]; }
  if (e == Nn) offs[Nn] = run;
}

__global__ void fill_kernel(const int* __restrict__ dst, const int* __restrict__ offs,
                            int* __restrict__ cnt, int* __restrict__ eid, int E) {
  int i = blockIdx.x * 256 + threadIdx.x;
  if (i < E) {
    int d = dst[i];
    int p = offs[d] + atomicAdd(&cnt[d], 1);
    eid[p] = i;
  }
}

// agg[node] = sum over CSR bucket of eabf rows (bf16 in, bf16 out). One wave/node.
__global__ __launch_bounds__(256) void agg_kernel(
    const unsigned short* __restrict__ eabf, const int* __restrict__ eid,
    const int* __restrict__ offs, unsigned short* __restrict__ aggbf, int Nn) {
  int node = blockIdx.x * 4 + (threadIdx.x >> 6);
  if (node >= Nn) return;
  int lane = threadIdx.x & 63;
  int s = offs[node], e = offs[node + 1];
  float4 acc = make_float4(0.f, 0.f, 0.f, 0.f);
  for (int i = s; i < e; ++i) {
    int ed = eid[i];
    ushort4 v = *(const ushort4*)(eabf + (size_t)ed * D + lane * 4);
    acc.x += bf2f(v.x); acc.y += bf2f(v.y); acc.z += bf2f(v.z); acc.w += bf2f(v.w);
  }
  ushort4 o;
  o.x = f2bf(acc.x); o.y = f2bf(acc.y); o.z = f2bf(acc.z); o.w = f2bf(acc.w);
  *(ushort4*)(aggbf + (size_t)node * D + lane * 4) = o;
}

// Fused 3-layer MLP, barrier-free K-loops:
//   res += LN(relu(relu(A@W1+b1)@W2+b2)@W3+b3)*g+b
// A = concat of NCHUNK bf16 256-wide chunks (chunk0 gather g0, chunk1 gather g1).
// W* in fragment-major layout (see wprep). A and B fragments load straight from
// global to registers, double-buffered; only h1/h2 round-trip through LDS.
// resid!=null: fp32 RMW + optional bf16 shadow. resid==null: bf16 RMW on bfout.
template<int NCHUNK>
__global__ __launch_bounds__(256, 3) void fused_mlp(
    const unsigned short* __restrict__ C0, const int* __restrict__ g0,
    const unsigned short* __restrict__ C1, const int* __restrict__ g1,
    const unsigned short* __restrict__ C2,
    const unsigned short* __restrict__ W1, const float* __restrict__ b1,
    const unsigned short* __restrict__ W2, const float* __restrict__ b2,
    const unsigned short* __restrict__ W3, const float* __restrict__ b3,
    const float* __restrict__ lng, const float* __restrict__ lnb,
    float* __restrict__ resid, unsigned short* __restrict__ bfout, int M)
{
  __shared__ __align__(16) unsigned short Hs[64 * 264];  // 33792 B, h1/h2 (+8 pad)
  __shared__ float ps1[256];
  __shared__ float ps2[256];

  const int tid  = threadIdx.x;
  const int lane = tid & 63;
  const int wave = tid >> 6;
  const int lr   = lane & 15;
  const int lq   = lane >> 4;
  const int r0   = blockIdx.x * 64;

  // per-lane A-row element offsets for the 4 m-tiles, per chunk
  int ro0[4], ro1[4], ro2[4];
  #pragma unroll
  for (int mt = 0; mt < 4; ++mt) {
    int rw = r0 + mt * 16 + lr;
    if (rw > M - 1) rw = M - 1;
    ro0[mt] = (g0 ? g0[rw] : rw) * D;
    ro1[mt] = (NCHUNK > 1) ? ((g1 ? g1[rw] : rw) * D) : 0;
    ro2[mt] = (NCHUNK > 2) ? rw * D : 0;
  }

  f32x4 acc[4][4];
  bf16x8 afc[4], bqc[4], afn[4], bqn[4];

  // B fragment loader: wave-coalesced 1KB segment per (kt, nt)
  const int ctb = wave * 4;   // this wave's first col-tile
  #define LOADB(Wp, kt, dst)                                                  \
    _Pragma("unroll")                                                         \
    for (int nt = 0; nt < 4; ++nt)                                            \
      dst[nt] = *(const bf16x8*)((Wp) + ((((kt) * 16 + ctb + nt) * 64 + lane) * 8));

  // A fragment loader (layer 1): per-lane 16B from gathered row
  #define LOADA(kt, dst) {                                                    \
    const int c_ = (kt) >> 3;                                                 \
    const int koff_ = (((kt) & 7) << 5) + lq * 8;                             \
    const unsigned short* bp_ = (c_ == 0) ? C0 : (c_ == 1 ? C1 : C2);         \
    _Pragma("unroll")                                                         \
    for (int mt = 0; mt < 4; ++mt) {                                          \
      int r_ = ro0[mt];                                                       \
      if (NCHUNK > 1 && c_ == 1) r_ = ro1[mt];                                \
      if (NCHUNK > 2 && c_ == 2) r_ = ro2[mt];                                \
      dst[mt] = *(const bf16x8*)(bp_ + r_ + koff_);                           \
    }                                                                         \
  }

  // ---------------- Layer 1 (K = NCHUNK*256) ----------------
  #pragma unroll
  for (int i = 0; i < 4; i++)
    #pragma unroll
    for (int j = 0; j < 4; j++)
      acc[i][j] = (f32x4){0.f, 0.f, 0.f, 0.f};

  constexpr int NKT = NCHUNK * 8;
  LOADA(0, afc);
  LOADB(W1, 0, bqc);
  #pragma unroll 2
  for (int kt = 0; kt < NKT; ++kt) {
    const int kn = (kt + 1 < NKT) ? kt + 1 : kt;
    LOADA(kn, afn);
    LOADB(W1, kn, bqn);
    #pragma unroll
    for (int mt = 0; mt < 4; ++mt)
      #pragma unroll
      for (int nt = 0; nt < 4; ++nt)
        acc[mt][nt] = __builtin_amdgcn_mfma_f32_16x16x32_bf16(afc[mt], bqc[nt], acc[mt][nt], 0, 0, 0);
    #pragma unroll
    for (int i = 0; i < 4; ++i) { afc[i] = afn[i]; bqc[i] = bqn[i]; }
  }
  // epilogue: bias + relu -> Hs (each wave owns cols wave*64..+63; no race)
  {
    float bv[4];
    #pragma unroll
    for (int nt = 0; nt < 4; ++nt) bv[nt] = b1[wave * 64 + nt * 16 + lr];
    #pragma unroll
    for (int mt = 0; mt < 4; ++mt)
      #pragma unroll
      for (int r = 0; r < 4; ++r) {
        const int row = mt * 16 + lq * 4 + r;
        #pragma unroll
        for (int nt = 0; nt < 4; ++nt) {
          float v = acc[mt][nt][r] + bv[nt];
          v = v > 0.f ? v : 0.f;
          Hs[row * 264 + wave * 64 + nt * 16 + lr] = f2bf(v);
        }
      }
  }
  __syncthreads();   // h1 visible to all waves

  // ---------------- Layer 2 (K = 256, A from Hs) ----------------
  #pragma unroll
  for (int i = 0; i < 4; i++)
    #pragma unroll
    for (int j = 0; j < 4; j++)
      acc[i][j] = (f32x4){0.f, 0.f, 0.f, 0.f};
  LOADB(W2, 0, bqc);
  #pragma unroll 2
  for (int kt = 0; kt < 8; ++kt) {
    const int kn = (kt + 1 < 8) ? kt + 1 : kt;
    LOADB(W2, kn, bqn);
    #pragma unroll
    for (int mt = 0; mt < 4; ++mt)
      afc[mt] = *(const bf16x8*)&Hs[(mt * 16 + lr) * 264 + (kt << 5) + lq * 8];
    #pragma unroll
    for (int mt = 0; mt < 4; ++mt)
      #pragma unroll
      for (int nt = 0; nt < 4; ++nt)
        acc[mt][nt] = __builtin_amdgcn_mfma_f32_16x16x32_bf16(afc[mt], bqc[nt], acc[mt][nt], 0, 0, 0);
    #pragma unroll
    for (int i = 0; i < 4; ++i) bqc[i] = bqn[i];
  }
  __syncthreads();   // all h1 reads done before overwrite
  {
    float bv[4];
    #pragma unroll
    for (int nt = 0; nt < 4; ++nt) bv[nt] = b2[wave * 64 + nt * 16 + lr];
    #pragma unroll
    for (int mt = 0; mt < 4; ++mt)
      #pragma unroll
      for (int r = 0; r < 4; ++r) {
        const int row = mt * 16 + lq * 4 + r;
        #pragma unroll
        for (int nt = 0; nt < 4; ++nt) {
          float v = acc[mt][nt][r] + bv[nt];
          v = v > 0.f ? v : 0.f;
          Hs[row * 264 + wave * 64 + nt * 16 + lr] = f2bf(v);
        }
      }
  }
  __syncthreads();   // h2 visible

  // ---------------- Layer 3 (K = 256) + LayerNorm + residual ----------------
  #pragma unroll
  for (int i = 0; i < 4; i++)
    #pragma unroll
    for (int j = 0; j < 4; j++)
      acc[i][j] = (f32x4){0.f, 0.f, 0.f, 0.f};
  LOADB(W3, 0, bqc);
  #pragma unroll 2
  for (int kt = 0; kt < 8; ++kt) {
    const int kn = (kt + 1 < 8) ? kt + 1 : kt;
    LOADB(W3, kn, bqn);
    #pragma unroll
    for (int mt = 0; mt < 4; ++mt)
      afc[mt] = *(const bf16x8*)&Hs[(mt * 16 + lr) * 264 + (kt << 5) + lq * 8];
    #pragma unroll
    for (int mt = 0; mt < 4; ++mt)
      #pragma unroll
      for (int nt = 0; nt < 4; ++nt)
        acc[mt][nt] = __builtin_amdgcn_mfma_f32_16x16x32_bf16(afc[mt], bqc[nt], acc[mt][nt], 0, 0, 0);
    #pragma unroll
    for (int i = 0; i < 4; ++i) bqc[i] = bqn[i];
  }
  // bias
  #pragma unroll
  for (int nt = 0; nt < 4; ++nt) {
    const float bv = b3[wave * 64 + nt * 16 + lr];
    #pragma unroll
    for (int mt = 0; mt < 4; ++mt)
      #pragma unroll
      for (int r = 0; r < 4; ++r)
        acc[mt][nt][r] += bv;
  }
  // LN stats
  #pragma unroll
  for (int mt = 0; mt < 4; ++mt) {
    #pragma unroll
    for (int r = 0; r < 4; ++r) {
      float s1 = 0.f, s2 = 0.f;
      #pragma unroll
      for (int nt = 0; nt < 4; ++nt) {
        float v = acc[mt][nt][r];
        s1 += v; s2 += v * v;
      }
      #pragma unroll
      for (int dlt = 1; dlt < 16; dlt <<= 1) {
        s1 += __shfl_xor(s1, dlt, 64);
        s2 += __shfl_xor(s2, dlt, 64);
      }
      if (lr == 0) {
        ps1[(mt * 16 + lq * 4 + r) * 4 + wave] = s1;
        ps2[(mt * 16 + lq * 4 + r) * 4 + wave] = s2;
      }
    }
  }
  __syncthreads();
  #pragma unroll
  for (int mt = 0; mt < 4; ++mt) {
    #pragma unroll
    for (int r = 0; r < 4; ++r) {
      const int rl = mt * 16 + lq * 4 + r;
      const int row = r0 + rl;
      float fs1 = ps1[rl * 4 + 0] + ps1[rl * 4 + 1] + ps1[rl * 4 + 2] + ps1[rl * 4 + 3];
      float fs2 = ps2[rl * 4 + 0] + ps2[rl * 4 + 1] + ps2[rl * 4 + 2] + ps2[rl * 4 + 3];
      float mean = fs1 * (1.f / 256.f);
      float var  = fs2 * (1.f / 256.f) - mean * mean;
      float rstd = rsqrtf(var + 1e-5f);
      if (row < M) {
        #pragma unroll
        for (int nt = 0; nt < 4; ++nt) {
          const int col = wave * 64 + nt * 16 + lr;
          float v = (acc[mt][nt][r] - mean) * rstd * lng[col] + lnb[col];
          if (resid) {
            float* rp = resid + (size_t)row * D + col;
            float nv = *rp + v;
            *rp = nv;
            if (bfout) bfout[(size_t)row * D + col] = f2bf(nv);
          } else {
            unsigned short* bp = bfout + (size_t)row * D + col;
            *bp = f2bf(bf2f(*bp) + v);
          }
        }
      }
    }
  }
  #undef LOADA
  #undef LOADB
}

extern "C" void kernel_launch(void* const* d_in, const int* in_sizes, int n_in,
                              void* d_out, int out_size, void* d_ws, size_t ws_size,
                              hipStream_t stream) {
  const float* x         = (const float*)d_in[0];
  const int*   eidx      = (const int*)d_in[1];
  const float* edge_attr = (const float*)d_in[2];
  const float* eW1 = (const float*)d_in[3];
  const float* eB1 = (const float*)d_in[4];
  const float* eW2 = (const float*)d_in[5];
  const float* eB2 = (const float*)d_in[6];
  const float* eW3 = (const float*)d_in[7];
  const float* eB3 = (const float*)d_in[8];
  const float* eLNg = (const float*)d_in[9];
  const float* eLNb = (const float*)d_in[10];
  const float* nW1 = (const float*)d_in[11];
  const float* nB1 = (const float*)d_in[12];
  const float* nW2 = (const float*)d_in[13];
  const float* nB2 = (const float*)d_in[14];
  const float* nW3 = (const float*)d_in[15];
  const float* nB3 = (const float*)d_in[16];
  const float* nLNg = (const float*)d_in[17];
  const float* nLNb = (const float*)d_in[18];

  const int Nn = in_sizes[0] / D;   // 10000
  const int E  = in_sizes[1] / 2;   // 60000
  const int B  = in_sizes[4] / D;   // 9

  const int* srcI = eidx;
  const int* dstI = eidx + E;

  char* wsp = (char*)d_ws;
  size_t off = 0;
  auto alloc = [&](size_t bytes) {
    char* p = wsp + off;
    off += (bytes + 255) & ~(size_t)255;
    return p;
  };
  unsigned short* eW1t = (unsigned short*)alloc((size_t)B * 768 * D * 2);
  unsigned short* eW2t = (unsigned short*)alloc((size_t)B * 256 * D * 2);
  unsigned short* eW3t = (unsigned short*)alloc((size_t)B * 256 * D * 2);
  unsigned short* nW1t = (unsigned short*)alloc((size_t)B * 512 * D * 2);
  unsigned short* nW2t = (unsigned short*)alloc((size_t)B * 256 * D * 2);
  unsigned short* nW3t = (unsigned short*)alloc((size_t)B * 256 * D * 2);
  unsigned short* eabf  = (unsigned short*)alloc((size_t)E * D * 2);
  unsigned short* xbf   = (unsigned short*)alloc((size_t)Nn * D * 2);
  unsigned short* aggbf = (unsigned short*)alloc((size_t)Nn * D * 2);
  int*            hist  = (int*)alloc((size_t)(Nn + 1) * 4);
  int*            offs  = (int*)alloc((size_t)(Nn + 1) * 4);
  int*            cnt   = (int*)alloc((size_t)Nn * 4);
  int*            eid   = (int*)alloc((size_t)E * 4);

  float* xbuf = (float*)d_out;  // x state lives in d_out

  auto wp = [&](const float* w, unsigned short* wt, int K) {
    int total = B * K * D;
    wprep_kernel<<<(total + 255) / 256, 256, 0, stream>>>(w, wt, K, total);
  };
  wp(eW1, eW1t, 768);
  wp(eW2, eW2t, 256);
  wp(eW3, eW3t, 256);
  wp(nW1, nW1t, 512);
  wp(nW2, nW2t, 256);
  wp(nW3, nW3t, 256);

  hipMemcpyAsync(xbuf, x, (size_t)Nn * D * 4, hipMemcpyDeviceToDevice, stream);
  {
    int n4 = E * D / 4;
    cvt_bf16_kernel<<<(n4 + 255) / 256, 256, 0, stream>>>(
        (const float4*)edge_attr, (ushort4*)eabf, n4);
    int m4 = Nn * D / 4;
    cvt_bf16_kernel<<<(m4 + 255) / 256, 256, 0, stream>>>(
        (const float4*)x, (ushort4*)xbf, m4);
  }

  // CSR build (edge_index constant across blocks -> once per launch)
  hipMemsetAsync(hist, 0, (size_t)Nn * 4, stream);
  hipMemsetAsync(cnt, 0, (size_t)Nn * 4, stream);
  hist_kernel<<<(E + 255) / 256, 256, 0, stream>>>(dstI, hist, E);
  scan_kernel<<<1, 256, 0, stream>>>(hist, offs, Nn);
  fill_kernel<<<(E + 255) / 256, 256, 0, stream>>>(dstI, offs, cnt, eid, E);

  const int gridE = (E + 63) / 64;
  const int gridN = (Nn + 63) / 64;
  const int gridA = (Nn + 3) / 4;

  for (int b = 0; b < B; ++b) {
    // edge: ea += LN(MLP([x[src], x[dst], ea]))  -- bf16 state RMW in eabf
    fused_mlp<3><<<gridE, 256, 0, stream>>>(
        xbf, srcI, xbf, dstI, eabf,
        eW1t + (size_t)b * 768 * D, eB1 + b * D,
        eW2t + (size_t)b * 256 * D, eB2 + b * D,
        eW3t + (size_t)b * 256 * D, eB3 + b * D,
        eLNg + b * D, eLNb + b * D, nullptr, eabf, E);
    // agg = segment_sum(ea, dst) via CSR gather (bf16 out)
    agg_kernel<<<gridA, 256, 0, stream>>>(eabf, eid, offs, aggbf, Nn);
    // node: x += LN(MLP([x, agg]))  -- fp32 RMW in xbuf + bf16 shadow xbf
    fused_mlp<2><<<gridN, 256, 0, stream>>>(
        xbf, nullptr, aggbf, nullptr, nullptr,
        nW1t + (size_t)b * 512 * D, nB1 + b * D,
        nW2t + (size_t)b * 256 * D, nB2 + b * D,
        nW3t + (size_t)b * 256 * D, nB3 + b * D,
        nLNg + b * D, nLNb + b * D, xbuf, xbf, Nn);
  }
}

// Round 6
// 1637.673 us; speedup vs baseline: 1.1490x; 1.1228x over previous
//
#include <hip/hip_runtime.h>

#define D 256

typedef __attribute__((ext_vector_type(8))) short bf16x8;
typedef __attribute__((ext_vector_type(4))) float f32x4;

__device__ inline unsigned short f2bf(float f) {
  union { float f; unsigned u; } v; v.f = f;
  unsigned r = v.u + 0x7FFFu + ((v.u >> 16) & 1u);
  return (unsigned short)(r >> 16);
}
__device__ inline float bf2f(unsigned short u) {
  union { unsigned u; float f; } v; v.u = ((unsigned)u) << 16;
  return v.f;
}

// Convert fp32 W[b][k][n] (n==D) -> bf16 fragment-major W':
//   W'[((kt*(D/16)+ct)*64 + lane)*8 + j]  where k=kt*32+(lane>>4)*8+j, col=ct*16+(lane&15)
__global__ void wprep_kernel(const float* __restrict__ w, unsigned short* __restrict__ wt,
                             int K, int total) {
  int idx = blockIdx.x * 256 + threadIdx.x;
  if (idx >= total) return;
  int per_b = K * D;
  int b = idx / per_b;
  int r = idx % per_b;
  int j = r & 7;
  int lane = (r >> 3) & 63;
  int t = r >> 9;            // kt*16 + ct
  int kt = t >> 4, ct = t & 15;
  int k = kt * 32 + (lane >> 4) * 8 + j;
  int col = ct * 16 + (lane & 15);
  wt[idx] = f2bf(w[((size_t)b * K + k) * D + col]);
}

__global__ void cvt_bf16_kernel(const float4* __restrict__ in, ushort4* __restrict__ out, int n4) {
  int i = blockIdx.x * 256 + threadIdx.x;
  if (i >= n4) return;
  float4 f = in[i];
  ushort4 o;
  o.x = f2bf(f.x); o.y = f2bf(f.y); o.z = f2bf(f.z); o.w = f2bf(f.w);
  out[i] = o;
}

// ---- CSR build ----
__global__ void hist_kernel(const int* __restrict__ dst, int* __restrict__ hist, int E) {
  int i = blockIdx.x * 256 + threadIdx.x;
  if (i < E) atomicAdd(&hist[dst[i]], 1);
}

__global__ void scan_kernel(const int* __restrict__ hist, int* __restrict__ offs, int Nn) {
  __shared__ int part[256];
  int t = threadIdx.x;
  int chunk = (Nn + 255) >> 8;
  int s = t * chunk;
  int e = s + chunk; if (e > Nn) e = Nn; if (s > Nn) s = Nn;
  int sum = 0;
  for (int i = s; i < e; ++i) sum += hist[i];
  part[t] = sum;
  __syncthreads();
  if (t == 0) {
    int run = 0;
    for (int i = 0; i < 256; ++i) { int v = part[i]; part[i] = run; run += v; }
  }
  __syncthreads();
  int run = part[t];
  for (int i = s; i < e; ++i) { offs[i] = run; run += hist[i]; }
  if (e == Nn) offs[Nn] = run;
}

__global__ void fill_kernel(const int* __restrict__ dst, const int* __restrict__ offs,
                            int* __restrict__ cnt, int* __restrict__ eid, int E) {
  int i = blockIdx.x * 256 + threadIdx.x;
  if (i < E) {
    int d = dst[i];
    int p = offs[d] + atomicAdd(&cnt[d], 1);
    eid[p] = i;
  }
}

// agg[node] = sum over CSR bucket of eabf rows (bf16 in, bf16 out). One wave/node.
__global__ __launch_bounds__(256) void agg_kernel(
    const unsigned short* __restrict__ eabf, const int* __restrict__ eid,
    const int* __restrict__ offs, unsigned short* __restrict__ aggbf, int Nn) {
  int node = blockIdx.x * 4 + (threadIdx.x >> 6);
  if (node >= Nn) return;
  int lane = threadIdx.x & 63;
  int s = offs[node], e = offs[node + 1];
  float4 acc = make_float4(0.f, 0.f, 0.f, 0.f);
  for (int i = s; i < e; ++i) {
    int ed = eid[i];
    ushort4 v = *(const ushort4*)(eabf + (size_t)ed * D + lane * 4);
    acc.x += bf2f(v.x); acc.y += bf2f(v.y); acc.z += bf2f(v.z); acc.w += bf2f(v.w);
  }
  ushort4 o;
  o.x = f2bf(acc.x); o.y = f2bf(acc.y); o.z = f2bf(acc.z); o.w = f2bf(acc.w);
  *(ushort4*)(aggbf + (size_t)node * D + lane * 4) = o;
}

// Fused 3-layer MLP, 32-row M-tile (2 m-frags/lane), barrier-free K-loops.
//   res += LN(relu(relu(A@W1+b1)@W2+b2)@W3+b3)*g+b
// A = concat of NCHUNK bf16 256-wide chunks (chunk0 gather g0, chunk1 gather g1).
// W* fragment-major (see wprep). A/B fragments load global->regs, double-buffered.
// resid!=null: fp32 RMW + optional bf16 shadow. resid==null: bf16 RMW on bfout.
template<int NCHUNK>
__global__ __launch_bounds__(256, 4) void fused_mlp(
    const unsigned short* __restrict__ C0, const int* __restrict__ g0,
    const unsigned short* __restrict__ C1, const int* __restrict__ g1,
    const unsigned short* __restrict__ C2,
    const unsigned short* __restrict__ W1, const float* __restrict__ b1,
    const unsigned short* __restrict__ W2, const float* __restrict__ b2,
    const unsigned short* __restrict__ W3, const float* __restrict__ b3,
    const float* __restrict__ lng, const float* __restrict__ lnb,
    float* __restrict__ resid, unsigned short* __restrict__ bfout, int M)
{
  __shared__ __align__(16) unsigned short Hs[32 * 264];  // 16896 B, h1/h2 (+8 pad)
  __shared__ float ps1[128];
  __shared__ float ps2[128];

  const int tid  = threadIdx.x;
  const int lane = tid & 63;
  const int wave = tid >> 6;
  const int lr   = lane & 15;
  const int lq   = lane >> 4;
  const int r0   = blockIdx.x * 32;

  // per-lane A-row element offsets for the 2 m-tiles, per chunk
  int ro0[2], ro1[2], ro2[2];
  #pragma unroll
  for (int mt = 0; mt < 2; ++mt) {
    int rw = r0 + mt * 16 + lr;
    if (rw > M - 1) rw = M - 1;
    ro0[mt] = (g0 ? g0[rw] : rw) * D;
    ro1[mt] = (NCHUNK > 1) ? ((g1 ? g1[rw] : rw) * D) : 0;
    ro2[mt] = (NCHUNK > 2) ? rw * D : 0;
  }

  f32x4 acc[2][4];
  bf16x8 afc[2], bqc[4], afn[2], bqn[4];

  const int ctb = wave * 4;   // this wave's first col-tile
  #define LOADB(Wp, kt, dst)                                                  \
    _Pragma("unroll")                                                         \
    for (int nt = 0; nt < 4; ++nt)                                            \
      dst[nt] = *(const bf16x8*)((Wp) + ((((kt) * 16 + ctb + nt) * 64 + lane) * 8));

  #define LOADA(kt, dst) {                                                    \
    const int c_ = (kt) >> 3;                                                 \
    const int koff_ = (((kt) & 7) << 5) + lq * 8;                             \
    const unsigned short* bp_ = (c_ == 0) ? C0 : (c_ == 1 ? C1 : C2);         \
    _Pragma("unroll")                                                         \
    for (int mt = 0; mt < 2; ++mt) {                                          \
      int r_ = ro0[mt];                                                       \
      if (NCHUNK > 1 && c_ == 1) r_ = ro1[mt];                                \
      if (NCHUNK > 2 && c_ == 2) r_ = ro2[mt];                                \
      dst[mt] = *(const bf16x8*)(bp_ + r_ + koff_);                           \
    }                                                                         \
  }

  // ---------------- Layer 1 (K = NCHUNK*256) ----------------
  #pragma unroll
  for (int i = 0; i < 2; i++)
    #pragma unroll
    for (int j = 0; j < 4; j++)
      acc[i][j] = (f32x4){0.f, 0.f, 0.f, 0.f};

  constexpr int NKT = NCHUNK * 8;
  LOADA(0, afc);
  LOADB(W1, 0, bqc);
  #pragma unroll 2
  for (int kt = 0; kt < NKT; ++kt) {
    const int kn = (kt + 1 < NKT) ? kt + 1 : kt;
    LOADA(kn, afn);
    LOADB(W1, kn, bqn);
    #pragma unroll
    for (int mt = 0; mt < 2; ++mt)
      #pragma unroll
      for (int nt = 0; nt < 4; ++nt)
        acc[mt][nt] = __builtin_amdgcn_mfma_f32_16x16x32_bf16(afc[mt], bqc[nt], acc[mt][nt], 0, 0, 0);
    #pragma unroll
    for (int i = 0; i < 2; ++i) afc[i] = afn[i];
    #pragma unroll
    for (int i = 0; i < 4; ++i) bqc[i] = bqn[i];
  }
  // epilogue: bias + relu -> Hs (each wave owns cols wave*64..+63; no race)
  {
    float bv[4];
    #pragma unroll
    for (int nt = 0; nt < 4; ++nt) bv[nt] = b1[wave * 64 + nt * 16 + lr];
    #pragma unroll
    for (int mt = 0; mt < 2; ++mt)
      #pragma unroll
      for (int r = 0; r < 4; ++r) {
        const int row = mt * 16 + lq * 4 + r;
        #pragma unroll
        for (int nt = 0; nt < 4; ++nt) {
          float v = acc[mt][nt][r] + bv[nt];
          v = v > 0.f ? v : 0.f;
          Hs[row * 264 + wave * 64 + nt * 16 + lr] = f2bf(v);
        }
      }
  }
  __syncthreads();   // h1 visible to all waves

  // ---------------- Layer 2 (K = 256, A from Hs) ----------------
  #pragma unroll
  for (int i = 0; i < 2; i++)
    #pragma unroll
    for (int j = 0; j < 4; j++)
      acc[i][j] = (f32x4){0.f, 0.f, 0.f, 0.f};
  LOADB(W2, 0, bqc);
  #pragma unroll 2
  for (int kt = 0; kt < 8; ++kt) {
    const int kn = (kt + 1 < 8) ? kt + 1 : kt;
    LOADB(W2, kn, bqn);
    #pragma unroll
    for (int mt = 0; mt < 2; ++mt)
      afc[mt] = *(const bf16x8*)&Hs[(mt * 16 + lr) * 264 + (kt << 5) + lq * 8];
    #pragma unroll
    for (int mt = 0; mt < 2; ++mt)
      #pragma unroll
      for (int nt = 0; nt < 4; ++nt)
        acc[mt][nt] = __builtin_amdgcn_mfma_f32_16x16x32_bf16(afc[mt], bqc[nt], acc[mt][nt], 0, 0, 0);
    #pragma unroll
    for (int i = 0; i < 4; ++i) bqc[i] = bqn[i];
  }
  __syncthreads();   // all h1 reads done before overwrite
  {
    float bv[4];
    #pragma unroll
    for (int nt = 0; nt < 4; ++nt) bv[nt] = b2[wave * 64 + nt * 16 + lr];
    #pragma unroll
    for (int mt = 0; mt < 2; ++mt)
      #pragma unroll
      for (int r = 0; r < 4; ++r) {
        const int row = mt * 16 + lq * 4 + r;
        #pragma unroll
        for (int nt = 0; nt < 4; ++nt) {
          float v = acc[mt][nt][r] + bv[nt];
          v = v > 0.f ? v : 0.f;
          Hs[row * 264 + wave * 64 + nt * 16 + lr] = f2bf(v);
        }
      }
  }
  __syncthreads();   // h2 visible

  // ---------------- Layer 3 (K = 256) + LayerNorm + residual ----------------
  #pragma unroll
  for (int i = 0; i < 2; i++)
    #pragma unroll
    for (int j = 0; j < 4; j++)
      acc[i][j] = (f32x4){0.f, 0.f, 0.f, 0.f};
  LOADB(W3, 0, bqc);
  #pragma unroll 2
  for (int kt = 0; kt < 8; ++kt) {
    const int kn = (kt + 1 < 8) ? kt + 1 : kt;
    LOADB(W3, kn, bqn);
    #pragma unroll
    for (int mt = 0; mt < 2; ++mt)
      afc[mt] = *(const bf16x8*)&Hs[(mt * 16 + lr) * 264 + (kt << 5) + lq * 8];
    #pragma unroll
    for (int mt = 0; mt < 2; ++mt)
      #pragma unroll
      for (int nt = 0; nt < 4; ++nt)
        acc[mt][nt] = __builtin_amdgcn_mfma_f32_16x16x32_bf16(afc[mt], bqc[nt], acc[mt][nt], 0, 0, 0);
    #pragma unroll
    for (int i = 0; i < 4; ++i) bqc[i] = bqn[i];
  }
  // bias
  #pragma unroll
  for (int nt = 0; nt < 4; ++nt) {
    const float bv = b3[wave * 64 + nt * 16 + lr];
    #pragma unroll
    for (int mt = 0; mt < 2; ++mt)
      #pragma unroll
      for (int r = 0; r < 4; ++r)
        acc[mt][nt][r] += bv;
  }
  // LN stats
  #pragma unroll
  for (int mt = 0; mt < 2; ++mt) {
    #pragma unroll
    for (int r = 0; r < 4; ++r) {
      float s1 = 0.f, s2 = 0.f;
      #pragma unroll
      for (int nt = 0; nt < 4; ++nt) {
        float v = acc[mt][nt][r];
        s1 += v; s2 += v * v;
      }
      #pragma unroll
      for (int dlt = 1; dlt < 16; dlt <<= 1) {
        s1 += __shfl_xor(s1, dlt, 64);
        s2 += __shfl_xor(s2, dlt, 64);
      }
      if (lr == 0) {
        ps1[(mt * 16 + lq * 4 + r) * 4 + wave] = s1;
        ps2[(mt * 16 + lq * 4 + r) * 4 + wave] = s2;
      }
    }
  }
  __syncthreads();
  #pragma unroll
  for (int mt = 0; mt < 2; ++mt) {
    #pragma unroll
    for (int r = 0; r < 4; ++r) {
      const int rl = mt * 16 + lq * 4 + r;
      const int row = r0 + rl;
      float fs1 = ps1[rl * 4 + 0] + ps1[rl * 4 + 1] + ps1[rl * 4 + 2] + ps1[rl * 4 + 3];
      float fs2 = ps2[rl * 4 + 0] + ps2[rl * 4 + 1] + ps2[rl * 4 + 2] + ps2[rl * 4 + 3];
      float mean = fs1 * (1.f / 256.f);
      float var  = fs2 * (1.f / 256.f) - mean * mean;
      float rstd = rsqrtf(var + 1e-5f);
      if (row < M) {
        #pragma unroll
        for (int nt = 0; nt < 4; ++nt) {
          const int col = wave * 64 + nt * 16 + lr;
          float v = (acc[mt][nt][r] - mean) * rstd * lng[col] + lnb[col];
          if (resid) {
            float* rp = resid + (size_t)row * D + col;
            float nv = *rp + v;
            *rp = nv;
            if (bfout) bfout[(size_t)row * D + col] = f2bf(nv);
          } else {
            unsigned short* bp = bfout + (size_t)row * D + col;
            *bp = f2bf(bf2f(*bp) + v);
          }
        }
      }
    }
  }
  #undef LOADA
  #undef LOADB
}

extern "C" void kernel_launch(void* const* d_in, const int* in_sizes, int n_in,
                              void* d_out, int out_size, void* d_ws, size_t ws_size,
                              hipStream_t stream) {
  const float* x         = (const float*)d_in[0];
  const int*   eidx      = (const int*)d_in[1];
  const float* edge_attr = (const float*)d_in[2];
  const float* eW1 = (const float*)d_in[3];
  const float* eB1 = (const float*)d_in[4];
  const float* eW2 = (const float*)d_in[5];
  const float* eB2 = (const float*)d_in[6];
  const float* eW3 = (const float*)d_in[7];
  const float* eB3 = (const float*)d_in[8];
  const float* eLNg = (const float*)d_in[9];
  const float* eLNb = (const float*)d_in[10];
  const float* nW1 = (const float*)d_in[11];
  const float* nB1 = (const float*)d_in[12];
  const float* nW2 = (const float*)d_in[13];
  const float* nB2 = (const float*)d_in[14];
  const float* nW3 = (const float*)d_in[15];
  const float* nB3 = (const float*)d_in[16];
  const float* nLNg = (const float*)d_in[17];
  const float* nLNb = (const float*)d_in[18];

  const int Nn = in_sizes[0] / D;   // 10000
  const int E  = in_sizes[1] / 2;   // 60000
  const int B  = in_sizes[4] / D;   // 9

  const int* srcI = eidx;
  const int* dstI = eidx + E;

  char* wsp = (char*)d_ws;
  size_t off = 0;
  auto alloc = [&](size_t bytes) {
    char* p = wsp + off;
    off += (bytes + 255) & ~(size_t)255;
    return p;
  };
  unsigned short* eW1t = (unsigned short*)alloc((size_t)B * 768 * D * 2);
  unsigned short* eW2t = (unsigned short*)alloc((size_t)B * 256 * D * 2);
  unsigned short* eW3t = (unsigned short*)alloc((size_t)B * 256 * D * 2);
  unsigned short* nW1t = (unsigned short*)alloc((size_t)B * 512 * D * 2);
  unsigned short* nW2t = (unsigned short*)alloc((size_t)B * 256 * D * 2);
  unsigned short* nW3t = (unsigned short*)alloc((size_t)B * 256 * D * 2);
  unsigned short* eabf  = (unsigned short*)alloc((size_t)E * D * 2);
  unsigned short* xbf   = (unsigned short*)alloc((size_t)Nn * D * 2);
  unsigned short* aggbf = (unsigned short*)alloc((size_t)Nn * D * 2);
  int*            hist  = (int*)alloc((size_t)(Nn + 1) * 4);
  int*            offs  = (int*)alloc((size_t)(Nn + 1) * 4);
  int*            cnt   = (int*)alloc((size_t)Nn * 4);
  int*            eid   = (int*)alloc((size_t)E * 4);

  float* xbuf = (float*)d_out;  // x state lives in d_out

  auto wp = [&](const float* w, unsigned short* wt, int K) {
    int total = B * K * D;
    wprep_kernel<<<(total + 255) / 256, 256, 0, stream>>>(w, wt, K, total);
  };
  wp(eW1, eW1t, 768);
  wp(eW2, eW2t, 256);
  wp(eW3, eW3t, 256);
  wp(nW1, nW1t, 512);
  wp(nW2, nW2t, 256);
  wp(nW3, nW3t, 256);

  hipMemcpyAsync(xbuf, x, (size_t)Nn * D * 4, hipMemcpyDeviceToDevice, stream);
  {
    int n4 = E * D / 4;
    cvt_bf16_kernel<<<(n4 + 255) / 256, 256, 0, stream>>>(
        (const float4*)edge_attr, (ushort4*)eabf, n4);
    int m4 = Nn * D / 4;
    cvt_bf16_kernel<<<(m4 + 255) / 256, 256, 0, stream>>>(
        (const float4*)x, (ushort4*)xbf, m4);
  }

  // CSR build (edge_index constant across blocks -> once per launch)
  hipMemsetAsync(hist, 0, (size_t)Nn * 4, stream);
  hipMemsetAsync(cnt, 0, (size_t)Nn * 4, stream);
  hist_kernel<<<(E + 255) / 256, 256, 0, stream>>>(dstI, hist, E);
  scan_kernel<<<1, 256, 0, stream>>>(hist, offs, Nn);
  fill_kernel<<<(E + 255) / 256, 256, 0, stream>>>(dstI, offs, cnt, eid, E);

  const int gridE = (E + 31) / 32;
  const int gridN = (Nn + 31) / 32;
  const int gridA = (Nn + 3) / 4;

  for (int b = 0; b < B; ++b) {
    // edge: ea += LN(MLP([x[src], x[dst], ea]))  -- bf16 state RMW in eabf
    fused_mlp<3><<<gridE, 256, 0, stream>>>(
        xbf, srcI, xbf, dstI, eabf,
        eW1t + (size_t)b * 768 * D, eB1 + b * D,
        eW2t + (size_t)b * 256 * D, eB2 + b * D,
        eW3t + (size_t)b * 256 * D, eB3 + b * D,
        eLNg + b * D, eLNb + b * D, nullptr, eabf, E);
    // agg = segment_sum(ea, dst) via CSR gather (bf16 out)
    agg_kernel<<<gridA, 256, 0, stream>>>(eabf, eid, offs, aggbf, Nn);
    // node: x += LN(MLP([x, agg]))  -- fp32 RMW in xbuf + bf16 shadow xbf
    fused_mlp<2><<<gridN, 256, 0, stream>>>(
        xbf, nullptr, aggbf, nullptr, nullptr,
        nW1t + (size_t)b * 512 * D, nB1 + b * D,
        nW2t + (size_t)b * 256 * D, nB2 + b * D,
        nW3t + (size_t)b * 256 * D, nB3 + b * D,
        nLNg + b * D, nLNb + b * D, xbuf, xbf, Nn);
  }
}